// Round 1
// baseline (620.956 us; speedup 1.0000x reference)
//
#include <hip/hip_runtime.h>
#include <math.h>

#define NB 32
#define NC 128
#define NL 8192
#define SQRT_L 90.50966799187809f

typedef float f32x4 __attribute__((ext_vector_type(4)));
typedef __bf16 bf16x8 __attribute__((ext_vector_type(8)));

// Split fp32 into bf16 hi + bf16 lo (residual). Compiler emits v_cvt_pk_bf16_f32
// pairs for the casts (guide T12: do NOT hand-write cvt_pk).
__device__ inline void split_bf16(const float* e, bf16x8& hi, bf16x8& lo) {
#pragma unroll
  for (int j = 0; j < 8; ++j) {
    float f = e[j];
    __bf16 h = (__bf16)f;
    hi[j] = h;
    lo[j] = (__bf16)(f - (float)h);
  }
}

// ---------------- Pass 1: G[b] = x[b] @ y[b]^T  (+ row sums sx, sy) ----------
// grid (32 k-chunks, NB), block 256 = 4 waves. Each block: full 128x128 partial
// over a K-chunk of 256, atomicAdd into G. Wave w owns M-tiles {2w, 2w+1} x all
// 8 N-tiles. A/B frags load 8 contiguous f32 along K (coalesced 128B/row).
__global__ __launch_bounds__(256) void k_pass1(
    const float* __restrict__ x, const float* __restrict__ y,
    float* __restrict__ G, float* __restrict__ sx, float* __restrict__ sy)
{
  const int b = blockIdx.y;
  const int k0 = blockIdx.x * 256;
  const int wave = threadIdx.x >> 6;
  const int lane = threadIdx.x & 63;
  const int lr = lane & 15;
  const int lk = (lane >> 4) * 8;

  const float* Xb = x + (size_t)b * NC * NL;
  const float* Yb = y + (size_t)b * NC * NL;

  f32x4 acc[2][8];
#pragma unroll
  for (int i = 0; i < 2; ++i)
#pragma unroll
    for (int j = 0; j < 8; ++j) acc[i][j] = (f32x4)0.f;

  float rsx[2] = {0.f, 0.f};
  float rsy[8] = {0.f,0.f,0.f,0.f,0.f,0.f,0.f,0.f};

#pragma unroll 2
  for (int step = 0; step < 8; ++step) {
    const int kk = k0 + step * 32 + lk;
    bf16x8 ah[2], al[2];
#pragma unroll
    for (int t = 0; t < 2; ++t) {
      const float* p = Xb + (size_t)(wave * 32 + t * 16 + lr) * NL + kk;
      float e[8];
#pragma unroll
      for (int j = 0; j < 8; ++j) e[j] = p[j];
#pragma unroll
      for (int j = 0; j < 8; ++j) rsx[t] += e[j];
      split_bf16(e, ah[t], al[t]);
    }
#pragma unroll
    for (int n = 0; n < 8; ++n) {
      const float* p = Yb + (size_t)(n * 16 + lr) * NL + kk;
      float e[8];
#pragma unroll
      for (int j = 0; j < 8; ++j) e[j] = p[j];
      if (wave == 0) {
#pragma unroll
        for (int j = 0; j < 8; ++j) rsy[n] += e[j];
      }
      bf16x8 bh, bl;
      split_bf16(e, bh, bl);
#pragma unroll
      for (int t = 0; t < 2; ++t) {
        acc[t][n] = __builtin_amdgcn_mfma_f32_16x16x32_bf16(ah[t], bh, acc[t][n], 0, 0, 0);
        acc[t][n] = __builtin_amdgcn_mfma_f32_16x16x32_bf16(ah[t], bl, acc[t][n], 0, 0, 0);
        acc[t][n] = __builtin_amdgcn_mfma_f32_16x16x32_bf16(al[t], bh, acc[t][n], 0, 0, 0);
      }
    }
  }

  float* Gb = G + (size_t)b * NC * NC;
  const int rq = (lane >> 4) * 4;  // C/D: col = lane&15, row = (lane>>4)*4 + r
#pragma unroll
  for (int t = 0; t < 2; ++t)
#pragma unroll
    for (int n = 0; n < 8; ++n)
#pragma unroll
      for (int r = 0; r < 4; ++r) {
        const int row = wave * 32 + t * 16 + rq + r;
        const int col = n * 16 + lr;
        atomicAdd(&Gb[row * NC + col], acc[t][n][r]);
      }

  // lanes {lr, lr+16, lr+32, lr+48} hold partials of the same row
#pragma unroll
  for (int t = 0; t < 2; ++t) {
    float v = rsx[t];
    v += __shfl_xor(v, 16);
    v += __shfl_xor(v, 32);
    if (lane < 16) atomicAdd(&sx[b * NC + wave * 32 + t * 16 + lr], v);
  }
  if (wave == 0) {
#pragma unroll
    for (int n = 0; n < 8; ++n) {
      float v = rsy[n];
      v += __shfl_xor(v, 16);
      v += __shfl_xor(v, 32);
      if (lane < 16) atomicAdd(&sy[b * NC + n * 16 + lr], v);
    }
  }
}

// ---------------- Pass 2a: H[b] = Wf @ G[b] ---------------------------------
// grid (8, NB), block 128. Block computes 16 rows of H.
__global__ __launch_bounds__(128) void k_p2a(
    const float* __restrict__ G, const float* __restrict__ Wf, float* __restrict__ H)
{
  const int b = blockIdx.y, o0 = blockIdx.x * 16, t = threadIdx.x;
  __shared__ float wf[16][NC];
  for (int i = t; i < 16 * NC; i += 128) wf[i >> 7][i & 127] = Wf[(o0 + (i >> 7)) * NC + (i & 127)];
  __syncthreads();
  const float* Gb = G + (size_t)b * NC * NC;
  float acc[16];
#pragma unroll
  for (int o = 0; o < 16; ++o) acc[o] = 0.f;
  for (int f = 0; f < NC; ++f) {
    float g = Gb[f * NC + t];
#pragma unroll
    for (int o = 0; o < 16; ++o) acc[o] += wf[o][f] * g;
  }
  float* Hb = H + (size_t)b * NC * NC;
#pragma unroll
  for (int o = 0; o < 16; ++o) Hb[(o0 + o) * NC + t] = acc[o];
}

// ---------------- Pass 2b: scores -> softmax -> attn -> Af|Aa (bf16 split), c
// scores[o][p] = sum_a H[o][a] Wa[p][a] + u[o] ba[p] + bf[o] v[p] + L bf[o] ba[p]
// attn = softmax(scores)/sqrt(L);  Af = attn@Wf, Aa = attn@Wa, c = attn@(bf+ba)
// grid (8, NB), block 128 (thread t = column p, then column f).
__global__ __launch_bounds__(128) void k_p2b(
    const float* __restrict__ H, const float* __restrict__ Wf, const float* __restrict__ Wa,
    const float* __restrict__ bfv, const float* __restrict__ bav,
    const float* __restrict__ sx, const float* __restrict__ sy,
    __bf16* __restrict__ Ah, __bf16* __restrict__ Al, float* __restrict__ cvec)
{
  const int b = blockIdx.y, o0 = blockIdx.x * 16, t = threadIdx.x;
  __shared__ float h[16][NC];
  __shared__ float s[16][NC];
  __shared__ float uo[16];
  const float* Hb = H + (size_t)b * NC * NC;
  for (int i = t; i < 16 * NC; i += 128) h[i >> 7][i & 127] = Hb[(o0 + (i >> 7)) * NC + (i & 127)];
  __syncthreads();

  // column p = t of scores, plus v[p]
  float acc[16];
#pragma unroll
  for (int o = 0; o < 16; ++o) acc[o] = 0.f;
  float v = 0.f;
  const float* syb = sy + b * NC;
  for (int a = 0; a < NC; ++a) {
    float wa = Wa[t * NC + a];
    v += wa * syb[a];
#pragma unroll
    for (int o = 0; o < 16; ++o) acc[o] += h[o][a] * wa;
  }
  if (t < 16) {
    float u = 0.f;
    const float* sxb = sx + b * NC;
    for (int f = 0; f < NC; ++f) u += Wf[(o0 + t) * NC + f] * sxb[f];
    uo[t] = u;
  }
  __syncthreads();
  const float bat = bav[t];
#pragma unroll
  for (int o = 0; o < 16; ++o) {
    const float bfo = bfv[o0 + o];
    s[o][t] = acc[o] + uo[o] * bat + bfo * v + (float)NL * bfo * bat;
  }
  __syncthreads();

  // softmax rows (16 threads, one per row) + c
  if (t < 16) {
    float m = -3.4e38f;
    for (int p = 0; p < NC; ++p) m = fmaxf(m, s[t][p]);
    float sum = 0.f;
    for (int p = 0; p < NC; ++p) sum += expf(s[t][p] - m);
    const float inv = 1.f / (sum * SQRT_L);
    float cv = 0.f;
    for (int p = 0; p < NC; ++p) {
      float a_ = expf(s[t][p] - m) * inv;
      s[t][p] = a_;
      cv += a_ * (bfv[p] + bav[p]);
    }
    cvec[b * NC + o0 + t] = cv;
  }
  __syncthreads();

  // Af/Aa column f = t
  float af[16], aa[16];
#pragma unroll
  for (int o = 0; o < 16; ++o) { af[o] = 0.f; aa[o] = 0.f; }
  for (int p = 0; p < NC; ++p) {
    float wfp = Wf[p * NC + t], wap = Wa[p * NC + t];
#pragma unroll
    for (int o = 0; o < 16; ++o) {
      float at = s[o][p];
      af[o] += at * wfp;
      aa[o] += at * wap;
    }
  }
#pragma unroll
  for (int o = 0; o < 16; ++o) {
    size_t off = ((size_t)b * NC + o0 + o) * 256 + t;
    float a1 = af[o];
    __bf16 h1 = (__bf16)a1;
    Ah[off] = h1; Al[off] = (__bf16)(a1 - (float)h1);
    float a2 = aa[o];
    __bf16 h2 = (__bf16)a2;
    Ah[off + NC] = h2; Al[off + NC] = (__bf16)(a2 - (float)h2);
  }
}

// ---------------- Pass 3: out[b] = [Af|Aa] @ [x;y] + c ----------------------
// grid (NL/256, NB), block 512 = 8 waves. Block tile = 128 (all OUT) x 256 (L).
// Wave w owns cols [w*32, w*32+32): 8 M-frags x 2 N-frags, K=256 in 8 steps.
__global__ __launch_bounds__(512) void k_pass3(
    const float* __restrict__ x, const float* __restrict__ y,
    const __bf16* __restrict__ Ah, const __bf16* __restrict__ Al,
    const float* __restrict__ cvec, float* __restrict__ out)
{
  const int b = blockIdx.y;
  const int l0 = blockIdx.x * 256;
  const int wave = threadIdx.x >> 6;
  const int lane = threadIdx.x & 63;
  const int lr = lane & 15;
  const int lk = (lane >> 4) * 8;
  const int col = l0 + wave * 32;

  f32x4 acc[8][2];
#pragma unroll
  for (int m = 0; m < 8; ++m)
#pragma unroll
    for (int n = 0; n < 2; ++n) acc[m][n] = (f32x4)0.f;

  const __bf16* Ahb = Ah + (size_t)b * NC * 256;
  const __bf16* Alb = Al + (size_t)b * NC * 256;

  for (int half = 0; half < 2; ++half) {
    const float* S = (half == 0 ? x : y) + (size_t)b * NC * NL;
    for (int ks = 0; ks < 4; ++ks) {
      const int kk = half * 128 + ks * 32 + lk;  // k within Acat
      const int krow = ks * 32 + lk;             // channel row within S
      bf16x8 ah[8], al[8];
#pragma unroll
      for (int m = 0; m < 8; ++m) {
        ah[m] = *(const bf16x8*)(Ahb + (size_t)(m * 16 + lr) * 256 + kk);
        al[m] = *(const bf16x8*)(Alb + (size_t)(m * 16 + lr) * 256 + kk);
      }
#pragma unroll
      for (int nt = 0; nt < 2; ++nt) {
        float e[8];
        const float* ps = S + (size_t)krow * NL + col + nt * 16 + lr;
#pragma unroll
        for (int j = 0; j < 8; ++j) e[j] = ps[(size_t)j * NL];
        bf16x8 bh, bl;
        split_bf16(e, bh, bl);
#pragma unroll
        for (int m = 0; m < 8; ++m) {
          acc[m][nt] = __builtin_amdgcn_mfma_f32_16x16x32_bf16(ah[m], bh, acc[m][nt], 0, 0, 0);
          acc[m][nt] = __builtin_amdgcn_mfma_f32_16x16x32_bf16(ah[m], bl, acc[m][nt], 0, 0, 0);
          acc[m][nt] = __builtin_amdgcn_mfma_f32_16x16x32_bf16(al[m], bh, acc[m][nt], 0, 0, 0);
        }
      }
    }
  }

  const int rq = (lane >> 4) * 4;
  float* outb = out + (size_t)b * NC * NL;
#pragma unroll
  for (int m = 0; m < 8; ++m) {
#pragma unroll
    for (int r = 0; r < 4; ++r) {
      const int row = m * 16 + rq + r;
      const float cv = cvec[b * NC + row];
#pragma unroll
      for (int nt = 0; nt < 2; ++nt) {
        outb[(size_t)row * NL + col + nt * 16 + lr] = acc[m][nt][r] + cv;
      }
    }
  }
}

extern "C" void kernel_launch(void* const* d_in, const int* in_sizes, int n_in,
                              void* d_out, int out_size, void* d_ws, size_t ws_size,
                              hipStream_t stream)
{
  const float* x  = (const float*)d_in[0];
  const float* y  = (const float*)d_in[1];
  const float* Wf = (const float*)d_in[2];
  const float* bfv = (const float*)d_in[3];
  const float* Wa = (const float*)d_in[4];
  const float* bav = (const float*)d_in[5];
  float* out = (float*)d_out;

  // ws layout (fp32 then bf16): G | sx | sy | H | c | Ah | Al  (~8.4 MB total)
  float* G  = (float*)d_ws;                    // NB*NC*NC
  float* sx = G + (size_t)NB * NC * NC;        // NB*NC
  float* sy = sx + NB * NC;                    // NB*NC
  float* H  = sy + NB * NC;                    // NB*NC*NC
  float* cv = H + (size_t)NB * NC * NC;        // NB*NC
  __bf16* Ah = (__bf16*)(cv + NB * NC);        // NB*NC*256
  __bf16* Al = Ah + (size_t)NB * NC * 256;     // NB*NC*256

  hipMemsetAsync(G, 0, ((size_t)NB * NC * NC + 2 * (size_t)NB * NC) * sizeof(float), stream);
  k_pass1<<<dim3(NL / 256, NB), 256, 0, stream>>>(x, y, G, sx, sy);
  k_p2a<<<dim3(8, NB), 128, 0, stream>>>(G, Wf, H);
  k_p2b<<<dim3(8, NB), 128, 0, stream>>>(H, Wf, Wa, bfv, bav, sx, sy, Ah, Al, cv);
  k_pass3<<<dim3(NL / 256, NB), 512, 0, stream>>>(x, y, Ah, Al, cv, out);
}

// Round 2
// 502.097 us; speedup vs baseline: 1.2367x; 1.2367x over previous
//
#include <hip/hip_runtime.h>
#include <math.h>

#define NB 32
#define NC 128
#define NL 8192
#define SQRT_L 90.50966799187809f

typedef float f32x4 __attribute__((ext_vector_type(4)));
typedef __bf16 bf16x8 __attribute__((ext_vector_type(8)));

__device__ inline void gload_lds16(const void* g, void* l) {
  __builtin_amdgcn_global_load_lds(
      (const __attribute__((address_space(1))) void*)g,
      (__attribute__((address_space(3))) void*)l, 16, 0, 0);
}

__device__ inline void split8(const float* e, bf16x8& hi, bf16x8& lo) {
#pragma unroll
  for (int j = 0; j < 8; ++j) {
    float f = e[j];
    __bf16 h = (__bf16)f;
    hi[j] = h;
    lo[j] = (__bf16)(f - (float)h);
  }
}

// ---------------- prep: split/transpose weights to bf16 hi/lo; zero G/sx/sy --
// ws8 order: Wf_h, Wf_l, WfT_h, WfT_l, Wa_h, Wa_l, WaT_h, WaT_l (each 128x128)
__global__ __launch_bounds__(256, 2) void k_prep(
    const float* __restrict__ Wf, const float* __restrict__ Wa,
    float* __restrict__ zbase, __bf16* __restrict__ ws8)
{
  const int blk = blockIdx.x, t = threadIdx.x;
  if (blk >= 2) {
    f32x4* z = (f32x4*)zbase;
    const int n4 = (NB * NC * NC + 2 * NB * NC) / 4;
    for (int i = (blk - 2) * 256 + t; i < n4; i += 10 * 256) z[i] = (f32x4)0.f;
    return;
  }
  const float* W = blk ? Wa : Wf;
  __bf16* Oh = ws8 + (blk ? 4 : 0) * 16384;
  __bf16* Ol = Oh + 16384;
  __bf16* Th = Ol + 16384;
  __bf16* Tl = Th + 16384;
  __shared__ float lds[NC * NC];
  for (int i = t; i < NC * NC; i += 256) {
    int r = i >> 7, c = i & 127;
    lds[r * 128 + (c ^ (r & 31))] = W[i];
  }
  __syncthreads();
  for (int i = t; i < NC * NC; i += 256) {
    int r = i >> 7, c = i & 127;
    float v = lds[r * 128 + (c ^ (r & 31))];
    __bf16 h = (__bf16)v;
    Oh[i] = h; Ol[i] = (__bf16)(v - (float)h);
    float vt = lds[c * 128 + (r ^ (c & 31))];  // W[c][r] -> T[r][c]
    __bf16 ht = (__bf16)vt;
    Th[i] = ht; Tl[i] = (__bf16)(vt - (float)ht);
  }
}

// ---------------- Pass 1: G[b] = x[b] @ y[b]^T (+ sx, sy), split-K=16 --------
// grid (16, NB), 256 thr = 4 waves. LDS-staged via global_load_lds, XOR swizzle.
__global__ __launch_bounds__(256, 2) void k_pass1(
    const float* __restrict__ x, const float* __restrict__ y,
    float* __restrict__ G, float* __restrict__ sx, float* __restrict__ sy)
{
  __shared__ float ldsA[2][128 * 32];
  __shared__ float ldsB[2][128 * 32];
  const int b = blockIdx.y;
  const int k0 = blockIdx.x * 512;
  const int tid = threadIdx.x;
  const int wave = tid >> 6, lane = tid & 63;
  const int lr = lane & 15, g = lane >> 4;
  const float* Xb = x + (size_t)b * NC * NL;
  const float* Yb = y + (size_t)b * NC * NL;

  // staging map: slot = q*256+tid -> row = slot>>3, phys chunk = slot&7,
  // logical chunk = phys ^ (row&7)  (16B chunks, 8 per 128B row)
  int srow[4], scol[4];
#pragma unroll
  for (int q = 0; q < 4; ++q) {
    int slot = q * 256 + tid;
    int row = slot >> 3, pch = slot & 7;
    srow[q] = row;
    scol[q] = (pch ^ (row & 7)) * 4;
  }

  f32x4 acc[2][8];
#pragma unroll
  for (int t = 0; t < 2; ++t)
#pragma unroll
    for (int n = 0; n < 8; ++n) acc[t][n] = (f32x4)0.f;
  float rsx[2] = {0.f, 0.f};
  float rsy[8] = {0.f, 0.f, 0.f, 0.f, 0.f, 0.f, 0.f, 0.f};

  auto stage = [&](int buf, int s) {
    const int kk = k0 + s * 32;
#pragma unroll
    for (int q = 0; q < 4; ++q)
      gload_lds16(Xb + (size_t)srow[q] * NL + kk + scol[q], &ldsA[buf][(q * 256 + tid) * 4]);
#pragma unroll
    for (int q = 0; q < 4; ++q)
      gload_lds16(Yb + (size_t)srow[q] * NL + kk + scol[q], &ldsB[buf][(q * 256 + tid) * 4]);
  };

  stage(0, 0);
  __syncthreads();

  for (int s = 0; s < 16; ++s) {
    const int cur = s & 1;
    if (s < 15) stage(cur ^ 1, s + 1);

    bf16x8 ah[2], al[2];
#pragma unroll
    for (int t = 0; t < 2; ++t) {
      const int row = wave * 32 + t * 16 + lr;
      const float* base = &ldsA[cur][row * 32];
      f32x4 v0 = *(const f32x4*)(base + ((2 * g) ^ (row & 7)) * 4);
      f32x4 v1 = *(const f32x4*)(base + ((2 * g + 1) ^ (row & 7)) * 4);
      float e[8] = {v0[0], v0[1], v0[2], v0[3], v1[0], v1[1], v1[2], v1[3]};
#pragma unroll
      for (int j = 0; j < 8; ++j) rsx[t] += e[j];
      split8(e, ah[t], al[t]);
    }
#pragma unroll
    for (int n = 0; n < 8; ++n) {
      const int row = n * 16 + lr;
      const float* base = &ldsB[cur][row * 32];
      f32x4 v0 = *(const f32x4*)(base + ((2 * g) ^ (row & 7)) * 4);
      f32x4 v1 = *(const f32x4*)(base + ((2 * g + 1) ^ (row & 7)) * 4);
      float e[8] = {v0[0], v0[1], v0[2], v0[3], v1[0], v1[1], v1[2], v1[3]};
      if (wave == 0) {
#pragma unroll
        for (int j = 0; j < 8; ++j) rsy[n] += e[j];
      }
      bf16x8 bh, bl;
      split8(e, bh, bl);
#pragma unroll
      for (int t = 0; t < 2; ++t) {
        acc[t][n] = __builtin_amdgcn_mfma_f32_16x16x32_bf16(ah[t], bh, acc[t][n], 0, 0, 0);
        acc[t][n] = __builtin_amdgcn_mfma_f32_16x16x32_bf16(ah[t], bl, acc[t][n], 0, 0, 0);
        acc[t][n] = __builtin_amdgcn_mfma_f32_16x16x32_bf16(al[t], bh, acc[t][n], 0, 0, 0);
      }
    }
    __syncthreads();
  }

  float* Gb = G + (size_t)b * NC * NC;
#pragma unroll
  for (int t = 0; t < 2; ++t)
#pragma unroll
    for (int n = 0; n < 8; ++n)
#pragma unroll
      for (int r = 0; r < 4; ++r) {
        const int row = wave * 32 + t * 16 + g * 4 + r;
        const int col = n * 16 + lr;
        atomicAdd(&Gb[row * NC + col], acc[t][n][r]);
      }
#pragma unroll
  for (int t = 0; t < 2; ++t) {
    float v = rsx[t];
    v += __shfl_xor(v, 16);
    v += __shfl_xor(v, 32);
    if (lane < 16) atomicAdd(&sx[b * NC + wave * 32 + t * 16 + lr], v);
  }
  if (wave == 0) {
#pragma unroll
    for (int n = 0; n < 8; ++n) {
      float v = rsy[n];
      v += __shfl_xor(v, 16);
      v += __shfl_xor(v, 32);
      if (lane < 16) atomicAdd(&sy[b * NC + n * 16 + lr], v);
    }
  }
}

// ---------------- Pass 2: Mt = Wa*G^T ; scores = Wf*Mt + rank1 ; softmax ;
//                  Af = attn*Wf, Aa = attn*Wa, c = attn*(bf+ba). 1 block/batch.
__global__ __launch_bounds__(256, 2) void k_p2(
    const float* __restrict__ G, const __bf16* __restrict__ ws8,
    const float* __restrict__ Wf, const float* __restrict__ Wa,
    const float* __restrict__ bfv, const float* __restrict__ bav,
    const float* __restrict__ sx, const float* __restrict__ sy,
    float* __restrict__ uv, __bf16* __restrict__ AhO, __bf16* __restrict__ AlO,
    float* __restrict__ cvec)
{
  __shared__ __bf16 sH[NC * NC];
  __shared__ __bf16 sL[NC * NC];
  const __bf16* Wf_h = ws8;
  const __bf16* Wf_l = ws8 + 16384;
  const __bf16* WfT_h = ws8 + 2 * 16384;
  const __bf16* WfT_l = ws8 + 3 * 16384;
  const __bf16* Wa_h = ws8 + 4 * 16384;
  const __bf16* Wa_l = ws8 + 5 * 16384;
  const __bf16* WaT_h = ws8 + 6 * 16384;
  const __bf16* WaT_l = ws8 + 7 * 16384;

  const int b = blockIdx.x;
  const int tid = threadIdx.x;
  const int wave = tid >> 6, lane = tid & 63;
  const int lr = lane & 15, g = lane >> 4;
  const int strip = wave * 32;

  // phase 0: u[o] = Wf . sx , v[o] = Wa . sy  -> uv[b][0..255]
  {
    const int o = tid & 127;
    const float* Wrow = (tid < 128 ? Wf : Wa) + o * NC;
    const float* sv = (tid < 128 ? sx : sy) + b * NC;
    const f32x4* W4 = (const f32x4*)Wrow;
    const f32x4* S4 = (const f32x4*)sv;
    float a = 0.f;
#pragma unroll
    for (int f4 = 0; f4 < 32; ++f4) {
      f32x4 w = W4[f4], s = S4[f4];
      a += w[0] * s[0] + w[1] * s[1] + w[2] * s[2] + w[3] * s[3];
    }
    uv[b * 256 + tid] = a;
  }

  const float* Gb = G + (size_t)b * NC * NC;

  // GEMM1: Mt[p][f] = sum_a Wa[p][a]*G[f][a] -> sH/sL (row=p, col=f, swizzled)
  {
    f32x4 a1[2][8];
#pragma unroll
    for (int t = 0; t < 2; ++t)
#pragma unroll
      for (int n = 0; n < 8; ++n) a1[t][n] = (f32x4)0.f;
#pragma unroll
    for (int ks = 0; ks < 4; ++ks) {
      const int a0 = ks * 32 + g * 8;
      bf16x8 wh[2], wl[2];
#pragma unroll
      for (int t = 0; t < 2; ++t) {
        const int p = strip + t * 16 + lr;
        wh[t] = *(const bf16x8*)(Wa_h + p * NC + a0);
        wl[t] = *(const bf16x8*)(Wa_l + p * NC + a0);
      }
#pragma unroll
      for (int n = 0; n < 8; ++n) {
        const int f = n * 16 + lr;
        f32x4 g0 = *(const f32x4*)(Gb + (size_t)f * NC + a0);
        f32x4 g1 = *(const f32x4*)(Gb + (size_t)f * NC + a0 + 4);
        float e[8] = {g0[0], g0[1], g0[2], g0[3], g1[0], g1[1], g1[2], g1[3]};
        bf16x8 gh, gl;
        split8(e, gh, gl);
#pragma unroll
        for (int t = 0; t < 2; ++t) {
          a1[t][n] = __builtin_amdgcn_mfma_f32_16x16x32_bf16(wh[t], gh, a1[t][n], 0, 0, 0);
          a1[t][n] = __builtin_amdgcn_mfma_f32_16x16x32_bf16(wh[t], gl, a1[t][n], 0, 0, 0);
          a1[t][n] = __builtin_amdgcn_mfma_f32_16x16x32_bf16(wl[t], gh, a1[t][n], 0, 0, 0);
        }
      }
    }
#pragma unroll
    for (int t = 0; t < 2; ++t)
#pragma unroll
      for (int n = 0; n < 8; ++n)
#pragma unroll
        for (int r = 0; r < 4; ++r) {
          const int p = strip + t * 16 + g * 4 + r;
          const int f = n * 16 + lr;
          const int idx = p * 128 + ((((f >> 3)) ^ (p & 7)) << 3) + (f & 7);
          float v = a1[t][n][r];
          __bf16 h = (__bf16)v;
          sH[idx] = h;
          sL[idx] = (__bf16)(v - (float)h);
        }
  }
  __syncthreads();

  // GEMM2: scores[o][p] = sum_f Wf[o][f]*Mt[p][f]
  f32x4 s2[2][8];
#pragma unroll
  for (int t = 0; t < 2; ++t)
#pragma unroll
    for (int n = 0; n < 8; ++n) s2[t][n] = (f32x4)0.f;
#pragma unroll
  for (int ks = 0; ks < 4; ++ks) {
    const int f0 = ks * 32 + g * 8;
    const int chunk = ks * 4 + g;
    bf16x8 wh[2], wl[2];
#pragma unroll
    for (int t = 0; t < 2; ++t) {
      const int o = strip + t * 16 + lr;
      wh[t] = *(const bf16x8*)(Wf_h + o * NC + f0);
      wl[t] = *(const bf16x8*)(Wf_l + o * NC + f0);
    }
#pragma unroll
    for (int n = 0; n < 8; ++n) {
      const int p = n * 16 + lr;
      const int idx = p * 128 + ((chunk ^ (p & 7)) << 3);
      bf16x8 mh = *(const bf16x8*)&sH[idx];
      bf16x8 ml = *(const bf16x8*)&sL[idx];
#pragma unroll
      for (int t = 0; t < 2; ++t) {
        s2[t][n] = __builtin_amdgcn_mfma_f32_16x16x32_bf16(wh[t], mh, s2[t][n], 0, 0, 0);
        s2[t][n] = __builtin_amdgcn_mfma_f32_16x16x32_bf16(wh[t], ml, s2[t][n], 0, 0, 0);
        s2[t][n] = __builtin_amdgcn_mfma_f32_16x16x32_bf16(wl[t], mh, s2[t][n], 0, 0, 0);
      }
    }
  }

  // rank-1 terms + softmax (row o distributed over 16 lr-lanes x 8 n-regs)
  float u_r[2][4], bf_r[2][4], v_c[8], ba_c[8], bb_c[8];
#pragma unroll
  for (int t = 0; t < 2; ++t)
#pragma unroll
    for (int r = 0; r < 4; ++r) {
      const int row = strip + t * 16 + g * 4 + r;
      u_r[t][r] = uv[b * 256 + row];
      bf_r[t][r] = bfv[row];
    }
#pragma unroll
  for (int n = 0; n < 8; ++n) {
    const int p = n * 16 + lr;
    v_c[n] = uv[b * 256 + 128 + p];
    ba_c[n] = bav[p];
    bb_c[n] = bfv[p] + bav[p];
  }
#pragma unroll
  for (int t = 0; t < 2; ++t)
#pragma unroll
    for (int n = 0; n < 8; ++n)
#pragma unroll
      for (int r = 0; r < 4; ++r)
        s2[t][n][r] += u_r[t][r] * ba_c[n] + bf_r[t][r] * (v_c[n] + 8192.0f * ba_c[n]);

  float cd[2][4];
#pragma unroll
  for (int t = 0; t < 2; ++t)
#pragma unroll
    for (int r = 0; r < 4; ++r) {
      float m = -3.4e38f;
#pragma unroll
      for (int n = 0; n < 8; ++n) m = fmaxf(m, s2[t][n][r]);
      m = fmaxf(m, __shfl_xor(m, 1));
      m = fmaxf(m, __shfl_xor(m, 2));
      m = fmaxf(m, __shfl_xor(m, 4));
      m = fmaxf(m, __shfl_xor(m, 8));
      float e[8], sum = 0.f;
#pragma unroll
      for (int n = 0; n < 8; ++n) { e[n] = __expf(s2[t][n][r] - m); sum += e[n]; }
      sum += __shfl_xor(sum, 1);
      sum += __shfl_xor(sum, 2);
      sum += __shfl_xor(sum, 4);
      sum += __shfl_xor(sum, 8);
      const float inv = 1.f / (sum * SQRT_L);
      float c = 0.f;
#pragma unroll
      for (int n = 0; n < 8; ++n) { float a = e[n] * inv; s2[t][n][r] = a; c += a * bb_c[n]; }
      c += __shfl_xor(c, 1);
      c += __shfl_xor(c, 2);
      c += __shfl_xor(c, 4);
      c += __shfl_xor(c, 8);
      cd[t][r] = c;
    }
  if (lr == 0) {
#pragma unroll
    for (int t = 0; t < 2; ++t)
#pragma unroll
      for (int r = 0; r < 4; ++r)
        cvec[b * NC + strip + t * 16 + g * 4 + r] = cd[t][r];
  }
  __syncthreads();  // all waves done reading Mt before overwrite

  // write attn -> sH/sL (row=o, col=p, swizzled)
#pragma unroll
  for (int t = 0; t < 2; ++t)
#pragma unroll
    for (int n = 0; n < 8; ++n)
#pragma unroll
      for (int r = 0; r < 4; ++r) {
        const int o = strip + t * 16 + g * 4 + r;
        const int p = n * 16 + lr;
        const int idx = o * 128 + ((((p >> 3)) ^ (o & 7)) << 3) + (p & 7);
        float a = s2[t][n][r];
        __bf16 h = (__bf16)a;
        sH[idx] = h;
        sL[idx] = (__bf16)(a - (float)h);
      }
  __syncthreads();

  // GEMM3a/b: Af = attn*Wf -> cols 0..127 ; Aa = attn*Wa -> cols 128..255
#pragma unroll
  for (int half = 0; half < 2; ++half) {
    const __bf16* Bh = half ? WaT_h : WfT_h;
    const __bf16* Bl = half ? WaT_l : WfT_l;
    f32x4 a3[2][8];
#pragma unroll
    for (int t = 0; t < 2; ++t)
#pragma unroll
      for (int n = 0; n < 8; ++n) a3[t][n] = (f32x4)0.f;
#pragma unroll
    for (int ks = 0; ks < 4; ++ks) {
      const int p0 = ks * 32 + g * 8;
      const int chunk = ks * 4 + g;
      bf16x8 th[2], tl[2];
#pragma unroll
      for (int t = 0; t < 2; ++t) {
        const int o = strip + t * 16 + lr;
        const int idx = o * 128 + ((chunk ^ (o & 7)) << 3);
        th[t] = *(const bf16x8*)&sH[idx];
        tl[t] = *(const bf16x8*)&sL[idx];
      }
#pragma unroll
      for (int n = 0; n < 8; ++n) {
        const int c = n * 16 + lr;
        bf16x8 bh = *(const bf16x8*)(Bh + c * NC + p0);
        bf16x8 bl = *(const bf16x8*)(Bl + c * NC + p0);
#pragma unroll
        for (int t = 0; t < 2; ++t) {
          a3[t][n] = __builtin_amdgcn_mfma_f32_16x16x32_bf16(th[t], bh, a3[t][n], 0, 0, 0);
          a3[t][n] = __builtin_amdgcn_mfma_f32_16x16x32_bf16(th[t], bl, a3[t][n], 0, 0, 0);
          a3[t][n] = __builtin_amdgcn_mfma_f32_16x16x32_bf16(tl[t], bh, a3[t][n], 0, 0, 0);
        }
      }
    }
#pragma unroll
    for (int t = 0; t < 2; ++t)
#pragma unroll
      for (int n = 0; n < 8; ++n)
#pragma unroll
        for (int r = 0; r < 4; ++r) {
          const int o = strip + t * 16 + g * 4 + r;
          const int c = half * 128 + n * 16 + lr;
          const size_t off = ((size_t)(b * NC + o)) * 256 + c;
          float v = a3[t][n][r];
          __bf16 h = (__bf16)v;
          AhO[off] = h;
          AlO[off] = (__bf16)(v - (float)h);
        }
  }
}

// ---------------- Pass 3: out[b] = [Af|Aa] @ [x;y] + c ----------------------
// grid (NL/128, NB), 512 thr = 8 waves (4 m-groups x 2 col-halves).
// S slice [32k x 128col] f32 LDS-staged (rotation swizzle), A from L2 per step.
__global__ __launch_bounds__(512, 4) void k_pass3(
    const float* __restrict__ x, const float* __restrict__ y,
    const __bf16* __restrict__ Ah, const __bf16* __restrict__ Al,
    const float* __restrict__ cvec, float* __restrict__ out)
{
  __shared__ float sS[2][32 * 128];
  const int b = blockIdx.y;
  const int l0 = blockIdx.x * 128;
  const int tid = threadIdx.x;
  const int wave = tid >> 6, lane = tid & 63;
  const int lr = lane & 15, g = lane >> 4;
  const int mg = wave >> 1, ch = wave & 1;

  // staging map: slot = q*512+tid -> k = slot>>5, phys chunk = slot&31 (16B),
  // logical chunk = (phys - 2*((k>>3)&3)) & 31  [rotation by 8 floats per g]
  int sk[2], sc[2];
#pragma unroll
  for (int q = 0; q < 2; ++q) {
    int slot = q * 512 + tid;
    int k = slot >> 5, pch = slot & 31;
    int gr = (k >> 3) & 3;
    sk[q] = k;
    sc[q] = ((pch - 2 * gr) & 31) * 4;
  }

  f32x4 acc[2][4];
#pragma unroll
  for (int t = 0; t < 2; ++t)
#pragma unroll
    for (int nt = 0; nt < 4; ++nt) acc[t][nt] = (f32x4)0.f;

  auto stage = [&](int buf, int s) {
    const float* S = (s < 4 ? x : y) + (size_t)b * NC * NL;
    const int chan0 = (s & 3) * 32;
#pragma unroll
    for (int q = 0; q < 2; ++q)
      gload_lds16(S + (size_t)(chan0 + sk[q]) * NL + l0 + sc[q],
                  &sS[buf][(q * 512 + tid) * 4]);
  };

  stage(0, 0);
  __syncthreads();

  for (int s = 0; s < 8; ++s) {
    const int cur = s & 1;
    if (s < 7) stage(cur ^ 1, s + 1);

    bf16x8 a_h[2], a_l[2];
#pragma unroll
    for (int t = 0; t < 2; ++t) {
      const size_t off = ((size_t)(b * NC + mg * 32 + t * 16 + lr)) * 256 + s * 32 + g * 8;
      a_h[t] = *(const bf16x8*)(Ah + off);
      a_l[t] = *(const bf16x8*)(Al + off);
    }
#pragma unroll
    for (int nt = 0; nt < 4; ++nt) {
      const int col = ch * 64 + nt * 16 + lr;
      const int base = ((((col >> 2) + 2 * g) & 31) << 2) + (col & 3);
      float e[8];
#pragma unroll
      for (int j = 0; j < 8; ++j) e[j] = sS[cur][(g * 8 + j) * 128 + base];
      bf16x8 bh, bl;
      split8(e, bh, bl);
#pragma unroll
      for (int t = 0; t < 2; ++t) {
        acc[t][nt] = __builtin_amdgcn_mfma_f32_16x16x32_bf16(a_h[t], bh, acc[t][nt], 0, 0, 0);
        acc[t][nt] = __builtin_amdgcn_mfma_f32_16x16x32_bf16(a_h[t], bl, acc[t][nt], 0, 0, 0);
        acc[t][nt] = __builtin_amdgcn_mfma_f32_16x16x32_bf16(a_l[t], bh, acc[t][nt], 0, 0, 0);
      }
    }
    __syncthreads();
  }

  float* outb = out + (size_t)b * NC * NL;
#pragma unroll
  for (int t = 0; t < 2; ++t)
#pragma unroll
    for (int r = 0; r < 4; ++r) {
      const int row = mg * 32 + t * 16 + g * 4 + r;
      const float cv = cvec[b * NC + row];
#pragma unroll
      for (int nt = 0; nt < 4; ++nt)
        outb[(size_t)row * NL + l0 + ch * 64 + nt * 16 + lr] = acc[t][nt][r] + cv;
    }
}

extern "C" void kernel_launch(void* const* d_in, const int* in_sizes, int n_in,
                              void* d_out, int out_size, void* d_ws, size_t ws_size,
                              hipStream_t stream)
{
  const float* x = (const float*)d_in[0];
  const float* y = (const float*)d_in[1];
  const float* Wf = (const float*)d_in[2];
  const float* bfv = (const float*)d_in[3];
  const float* Wa = (const float*)d_in[4];
  const float* bav = (const float*)d_in[5];
  float* out = (float*)d_out;

  // ws: G | sx | sy | uv | c | 8x weight-splits (bf16) | Ah | Al
  float* G = (float*)d_ws;                       // NB*NC*NC
  float* sx = G + (size_t)NB * NC * NC;          // NB*NC
  float* sy = sx + NB * NC;                      // NB*NC
  float* uv = sy + NB * NC;                      // NB*256
  float* cv = uv + NB * 256;                     // NB*NC
  __bf16* ws8 = (__bf16*)(cv + NB * NC);         // 8 * 16384 bf16
  __bf16* Ah = ws8 + 8 * 16384;                  // NB*NC*256
  __bf16* Al = Ah + (size_t)NB * NC * 256;       // NB*NC*256

  k_prep<<<12, 256, 0, stream>>>(Wf, Wa, G, ws8);
  k_pass1<<<dim3(16, NB), 256, 0, stream>>>(x, y, G, sx, sy);
  k_p2<<<NB, 256, 0, stream>>>(G, ws8, Wf, Wa, bfv, bav, sx, sy, uv, Ah, Al, cv);
  k_pass3<<<dim3(NL / 128, NB), 512, 0, stream>>>(x, y, Ah, Al, cv, out);
}

// Round 4
// 449.089 us; speedup vs baseline: 1.3827x; 1.1180x over previous
//
#include <hip/hip_runtime.h>
#include <math.h>

#define NB 32
#define NC 128
#define NL 8192
#define SQRT_L 90.50966799187809f

typedef float f32x4 __attribute__((ext_vector_type(4)));
typedef __bf16 bf16x8 __attribute__((ext_vector_type(8)));

#define BAR() __builtin_amdgcn_s_barrier()

__device__ inline void gload_lds16(const void* g, void* l) {
  __builtin_amdgcn_global_load_lds(
      (const __attribute__((address_space(1))) void*)g,
      (__attribute__((address_space(3))) void*)l, 16, 0, 0);
}

__device__ inline void split8(const float* e, bf16x8& hi, bf16x8& lo) {
#pragma unroll
  for (int j = 0; j < 8; ++j) {
    float f = e[j];
    __bf16 h = (__bf16)f;
    hi[j] = h;
    lo[j] = (__bf16)(f - (float)h);
  }
}

// ---------------- prep: split/transpose weights to bf16 hi/lo; zero G/sx/sy --
// ws8 order: Wf_h, Wf_l, WfT_h, WfT_l, Wa_h, Wa_l, WaT_h, WaT_l (each 128x128)
__global__ __launch_bounds__(256, 2) void k_prep(
    const float* __restrict__ Wf, const float* __restrict__ Wa,
    float* __restrict__ zbase, __bf16* __restrict__ ws8)
{
  const int blk = blockIdx.x, t = threadIdx.x;
  if (blk >= 2) {
    f32x4* z = (f32x4*)zbase;
    const int n4 = (NB * NC * NC + 2 * NB * NC) / 4;
    for (int i = (blk - 2) * 256 + t; i < n4; i += 10 * 256) z[i] = (f32x4)0.f;
    return;
  }
  const float* W = blk ? Wa : Wf;
  __bf16* Oh = ws8 + (blk ? 4 : 0) * 16384;
  __bf16* Ol = Oh + 16384;
  __bf16* Th = Ol + 16384;
  __bf16* Tl = Th + 16384;
  __shared__ float lds[NC * NC];
  for (int i = t; i < NC * NC; i += 256) {
    int r = i >> 7, c = i & 127;
    lds[r * 128 + (c ^ (r & 31))] = W[i];
  }
  __syncthreads();
  for (int i = t; i < NC * NC; i += 256) {
    int r = i >> 7, c = i & 127;
    float v = lds[r * 128 + (c ^ (r & 31))];
    __bf16 h = (__bf16)v;
    Oh[i] = h; Ol[i] = (__bf16)(v - (float)h);
    float vt = lds[c * 128 + (r ^ (c & 31))];  // W[c][r] -> T[r][c]
    __bf16 ht = (__bf16)vt;
    Th[i] = ht; Tl[i] = (__bf16)(vt - (float)ht);
  }
}

// ---------------- Pass 1: G[b] = x[b] @ y[b]^T (+ sx, sy), split-K=16 --------
// grid (16, NB), 512 thr = 8 waves; wave w owns rows [16w,16w+16).
// Counted-vmcnt double-buffer pipeline: stage(s+2) issued after compute(s);
// wait vmcnt(4) (= next stage's loads) at top — never drain to 0 mid-loop.
__global__ __launch_bounds__(512, 2) void k_pass1(
    const float* __restrict__ x, const float* __restrict__ y,
    float* __restrict__ G, float* __restrict__ sx, float* __restrict__ sy)
{
  __shared__ float ldsA[2][128 * 32];
  __shared__ float ldsB[2][128 * 32];
  const int b = blockIdx.y;
  const int k0 = blockIdx.x * 512;
  const int tid = threadIdx.x;
  const int wave = tid >> 6, lane = tid & 63;
  const int lr = lane & 15, g = lane >> 4;
  const float* Xb = x + (size_t)b * NC * NL;
  const float* Yb = y + (size_t)b * NC * NL;

  // staging map: slot = q*512+tid -> row = slot>>3, phys chunk = slot&7,
  // logical chunk = phys ^ (row&7)  (16B chunks, 8 per 128B row)
  int srow[2], scol[2];
#pragma unroll
  for (int q = 0; q < 2; ++q) {
    int slot = q * 512 + tid;
    int row = slot >> 3, pch = slot & 7;
    srow[q] = row;
    scol[q] = (pch ^ (row & 7)) * 4;
  }

  f32x4 acc[8];
#pragma unroll
  for (int n = 0; n < 8; ++n) acc[n] = (f32x4)0.f;
  float rsx = 0.f;
  float rsy[8] = {0.f, 0.f, 0.f, 0.f, 0.f, 0.f, 0.f, 0.f};

  auto stage = [&](int buf, int s) {
    const int kk = k0 + s * 32;
#pragma unroll
    for (int q = 0; q < 2; ++q)
      gload_lds16(Xb + (size_t)srow[q] * NL + kk + scol[q], &ldsA[buf][(q * 512 + tid) * 4]);
#pragma unroll
    for (int q = 0; q < 2; ++q)
      gload_lds16(Yb + (size_t)srow[q] * NL + kk + scol[q], &ldsB[buf][(q * 512 + tid) * 4]);
  };

  stage(0, 0);
  stage(1, 1);

  for (int s = 0; s < 16; ++s) {
    const int cur = s & 1;
    if (s < 15) { asm volatile("s_waitcnt vmcnt(4)" ::: "memory"); }
    else        { asm volatile("s_waitcnt vmcnt(0)" ::: "memory"); }
    BAR();

    bf16x8 ah, al;
    {
      const int row = wave * 16 + lr;
      const float* base = &ldsA[cur][row * 32];
      f32x4 v0 = *(const f32x4*)(base + ((2 * g) ^ (row & 7)) * 4);
      f32x4 v1 = *(const f32x4*)(base + ((2 * g + 1) ^ (row & 7)) * 4);
      float e[8] = {v0[0], v0[1], v0[2], v0[3], v1[0], v1[1], v1[2], v1[3]};
#pragma unroll
      for (int j = 0; j < 8; ++j) rsx += e[j];
      split8(e, ah, al);
    }
    __builtin_amdgcn_s_setprio(1);
#pragma unroll
    for (int n = 0; n < 8; ++n) {
      const int row = n * 16 + lr;
      const float* base = &ldsB[cur][row * 32];
      f32x4 v0 = *(const f32x4*)(base + ((2 * g) ^ (row & 7)) * 4);
      f32x4 v1 = *(const f32x4*)(base + ((2 * g + 1) ^ (row & 7)) * 4);
      float e[8] = {v0[0], v0[1], v0[2], v0[3], v1[0], v1[1], v1[2], v1[3]};
      if (wave == 0) {
#pragma unroll
        for (int j = 0; j < 8; ++j) rsy[n] += e[j];
      }
      bf16x8 bh, bl;
      split8(e, bh, bl);
      acc[n] = __builtin_amdgcn_mfma_f32_16x16x32_bf16(ah, bh, acc[n], 0, 0, 0);
      acc[n] = __builtin_amdgcn_mfma_f32_16x16x32_bf16(ah, bl, acc[n], 0, 0, 0);
      acc[n] = __builtin_amdgcn_mfma_f32_16x16x32_bf16(al, bh, acc[n], 0, 0, 0);
    }
    __builtin_amdgcn_s_setprio(0);
    asm volatile("s_waitcnt lgkmcnt(0)" ::: "memory");
    BAR();
    if (s < 14) stage(cur, s + 2);
  }

  float* Gb = G + (size_t)b * NC * NC;
#pragma unroll
  for (int n = 0; n < 8; ++n)
#pragma unroll
    for (int r = 0; r < 4; ++r) {
      const int row = wave * 16 + g * 4 + r;
      const int col = n * 16 + lr;
      atomicAdd(&Gb[row * NC + col], acc[n][r]);
    }
  {
    float v = rsx;
    v += __shfl_xor(v, 16);
    v += __shfl_xor(v, 32);
    if (lane < 16) atomicAdd(&sx[b * NC + wave * 16 + lr], v);
  }
  if (wave == 0) {
#pragma unroll
    for (int n = 0; n < 8; ++n) {
      float v = rsy[n];
      v += __shfl_xor(v, 16);
      v += __shfl_xor(v, 32);
      if (lane < 16) atomicAdd(&sy[b * NC + n * 16 + lr], v);
    }
  }
}

// ---------------- Pass 2 (strip-parallel): grid (4, NB), 256 thr = 4 waves.
// Each block: full Mt = Wa*G^T (shared work, tiny), then its own 32-row strip:
// scores -> softmax -> attn -> Af|Aa into step-grouped A-layout.
// A layout: elem((b,o,c)) = ((b*128+o)*8 + (c>>5))*64 + (c&31) [+32 for lo]
__global__ __launch_bounds__(256, 2) void k_p2(
    const float* __restrict__ G, const __bf16* __restrict__ ws8,
    const float* __restrict__ Wf, const float* __restrict__ Wa,
    const float* __restrict__ bfv, const float* __restrict__ bav,
    const float* __restrict__ sx, const float* __restrict__ sy,
    __bf16* __restrict__ Aout, float* __restrict__ cvec)
{
  __shared__ __bf16 sMtH[NC * NC];   // 32KB; attn-hi reuses [0:4096]
  __shared__ __bf16 sMtL[NC * NC];   // 32KB; attn-lo reuses [0:4096]
  __shared__ float sSc[32 * 128];    // 16KB scores
  __shared__ float su[32];
  __shared__ float sv[128];

  const __bf16* Wf_h = ws8;
  const __bf16* Wf_l = ws8 + 16384;
  const __bf16* WfT_h = ws8 + 2 * 16384;
  const __bf16* WfT_l = ws8 + 3 * 16384;
  const __bf16* Wa_h = ws8 + 4 * 16384;
  const __bf16* Wa_l = ws8 + 5 * 16384;
  const __bf16* WaT_h = ws8 + 6 * 16384;
  const __bf16* WaT_l = ws8 + 7 * 16384;

  const int b = blockIdx.y;
  const int so0 = blockIdx.x * 32;
  const int tid = threadIdx.x;
  const int wave = tid >> 6, lane = tid & 63;
  const int lr = lane & 15, g = lane >> 4;

  // phase 0: su[o'] = Wf[so0+o'] . sx ; sv[p] = Wa[p] . sy
  if (tid < 32) {
    const f32x4* W4 = (const f32x4*)(Wf + (size_t)(so0 + tid) * NC);
    const f32x4* S4 = (const f32x4*)(sx + b * NC);
    float a = 0.f;
#pragma unroll
    for (int i = 0; i < 32; ++i) {
      f32x4 w = W4[i], s = S4[i];
      a += w[0] * s[0] + w[1] * s[1] + w[2] * s[2] + w[3] * s[3];
    }
    su[tid] = a;
  } else if (tid >= 128) {
    const int p = tid - 128;
    const f32x4* W4 = (const f32x4*)(Wa + (size_t)p * NC);
    const f32x4* S4 = (const f32x4*)(sy + b * NC);
    float a = 0.f;
#pragma unroll
    for (int i = 0; i < 32; ++i) {
      f32x4 w = W4[i], s = S4[i];
      a += w[0] * s[0] + w[1] * s[1] + w[2] * s[2] + w[3] * s[3];
    }
    sv[p] = a;
  }

  const float* Gb = G + (size_t)b * NC * NC;

  // GEMM1: Mt[p][f] = sum_a Wa[p][a]*G[f][a]; wave owns p-strip [32w,32w+32)
  {
    f32x4 a1[2][8];
#pragma unroll
    for (int t = 0; t < 2; ++t)
#pragma unroll
      for (int n = 0; n < 8; ++n) a1[t][n] = (f32x4)0.f;
#pragma unroll
    for (int ks = 0; ks < 4; ++ks) {
      const int a0 = ks * 32 + g * 8;
      bf16x8 wh[2], wl[2];
#pragma unroll
      for (int t = 0; t < 2; ++t) {
        const int p = wave * 32 + t * 16 + lr;
        wh[t] = *(const bf16x8*)(Wa_h + p * NC + a0);
        wl[t] = *(const bf16x8*)(Wa_l + p * NC + a0);
      }
#pragma unroll
      for (int n = 0; n < 8; ++n) {
        const int f = n * 16 + lr;
        f32x4 g0 = *(const f32x4*)(Gb + (size_t)f * NC + a0);
        f32x4 g1 = *(const f32x4*)(Gb + (size_t)f * NC + a0 + 4);
        float e[8] = {g0[0], g0[1], g0[2], g0[3], g1[0], g1[1], g1[2], g1[3]};
        bf16x8 gh, gl;
        split8(e, gh, gl);
#pragma unroll
        for (int t = 0; t < 2; ++t) {
          a1[t][n] = __builtin_amdgcn_mfma_f32_16x16x32_bf16(wh[t], gh, a1[t][n], 0, 0, 0);
          a1[t][n] = __builtin_amdgcn_mfma_f32_16x16x32_bf16(wh[t], gl, a1[t][n], 0, 0, 0);
          a1[t][n] = __builtin_amdgcn_mfma_f32_16x16x32_bf16(wl[t], gh, a1[t][n], 0, 0, 0);
        }
      }
    }
#pragma unroll
    for (int t = 0; t < 2; ++t)
#pragma unroll
      for (int n = 0; n < 8; ++n)
#pragma unroll
        for (int r = 0; r < 4; ++r) {
          const int p = wave * 32 + t * 16 + g * 4 + r;
          const int f = n * 16 + lr;
          const int idx = p * 128 + (((f >> 3) ^ (p & 7)) << 3) + (f & 7);
          float v = a1[t][n][r];
          __bf16 h = (__bf16)v;
          sMtH[idx] = h;
          sMtL[idx] = (__bf16)(v - (float)h);
        }
  }
  __syncthreads();

  // GEMM2: scores[o][p] = sum_f Wf[o][f]*Mt[p][f]; o in strip, wave owns 2 p-frags
  f32x4 s2[2][2];
#pragma unroll
  for (int t = 0; t < 2; ++t)
#pragma unroll
    for (int n = 0; n < 2; ++n) s2[t][n] = (f32x4)0.f;
#pragma unroll
  for (int ks = 0; ks < 4; ++ks) {
    const int f0 = ks * 32 + g * 8;
    const int chunk = ks * 4 + g;
    bf16x8 wh[2], wl[2];
#pragma unroll
    for (int t = 0; t < 2; ++t) {
      const int o = so0 + t * 16 + lr;
      wh[t] = *(const bf16x8*)(Wf_h + o * NC + f0);
      wl[t] = *(const bf16x8*)(Wf_l + o * NC + f0);
    }
#pragma unroll
    for (int n = 0; n < 2; ++n) {
      const int p = (wave * 2 + n) * 16 + lr;
      const int idx = p * 128 + ((chunk ^ (p & 7)) << 3);
      bf16x8 mh = *(const bf16x8*)&sMtH[idx];
      bf16x8 ml = *(const bf16x8*)&sMtL[idx];
#pragma unroll
      for (int t = 0; t < 2; ++t) {
        s2[t][n] = __builtin_amdgcn_mfma_f32_16x16x32_bf16(wh[t], mh, s2[t][n], 0, 0, 0);
        s2[t][n] = __builtin_amdgcn_mfma_f32_16x16x32_bf16(wh[t], ml, s2[t][n], 0, 0, 0);
        s2[t][n] = __builtin_amdgcn_mfma_f32_16x16x32_bf16(wl[t], mh, s2[t][n], 0, 0, 0);
      }
    }
  }
  __syncthreads();  // all waves done reading Mt (attn will overwrite region)

  // rank-1 terms, write scores f32 to sSc
#pragma unroll
  for (int n = 0; n < 2; ++n) {
    const int p = (wave * 2 + n) * 16 + lr;
    const float bap = bav[p];
    const float svp = sv[p] + 8192.0f * bap;
#pragma unroll
    for (int t = 0; t < 2; ++t)
#pragma unroll
      for (int r = 0; r < 4; ++r) {
        const int o_ = t * 16 + g * 4 + r;
        sSc[o_ * 128 + p] = s2[t][n][r] + su[o_] * bap + bfv[so0 + o_] * svp;
      }
  }
  __syncthreads();

  // softmax: row = tid>>3 (32 rows), j = tid&7 scans 16 cols; 8-lane reduce
  {
    const int row = tid >> 3, j = tid & 7;
    const float* sr = &sSc[row * 128 + j * 16];
    float m = -3.4e38f;
#pragma unroll
    for (int i = 0; i < 16; ++i) m = fmaxf(m, sr[i]);
    m = fmaxf(m, __shfl_xor(m, 1));
    m = fmaxf(m, __shfl_xor(m, 2));
    m = fmaxf(m, __shfl_xor(m, 4));
    float e[16], sum = 0.f;
#pragma unroll
    for (int i = 0; i < 16; ++i) { e[i] = __expf(sr[i] - m); sum += e[i]; }
    sum += __shfl_xor(sum, 1);
    sum += __shfl_xor(sum, 2);
    sum += __shfl_xor(sum, 4);
    const float inv = 1.f / (sum * SQRT_L);
    float c = 0.f;
    bf16x8 hv[2], lv[2];
#pragma unroll
    for (int i = 0; i < 16; ++i) {
      const int p = j * 16 + i;
      float a = e[i] * inv;
      c += a * (bfv[p] + bav[p]);
      __bf16 h = (__bf16)a;
      hv[i >> 3][i & 7] = h;
      lv[i >> 3][i & 7] = (__bf16)(a - (float)h);
    }
    // attn LDS (reuse sMt[0:4096]): row stride 128 elems, 16-chunk XOR swizzle
#pragma unroll
    for (int q = 0; q < 2; ++q) {
      const int chunk = (j * 2 + q) ^ (row & 15);
      *(bf16x8*)&sMtH[row * 128 + chunk * 8] = hv[q];
      *(bf16x8*)&sMtL[row * 128 + chunk * 8] = lv[q];
    }
    c += __shfl_xor(c, 1);
    c += __shfl_xor(c, 2);
    c += __shfl_xor(c, 4);
    if (j == 0) cvec[b * NC + so0 + row] = c;
  }
  __syncthreads();

  // GEMM3: Af = attn*WfT (cols 0..127), Aa = attn*WaT (cols 128..255)
#pragma unroll
  for (int half = 0; half < 2; ++half) {
    const __bf16* Bh = half ? WaT_h : WfT_h;
    const __bf16* Bl = half ? WaT_l : WfT_l;
    f32x4 a3[2][2];
#pragma unroll
    for (int t = 0; t < 2; ++t)
#pragma unroll
      for (int n = 0; n < 2; ++n) a3[t][n] = (f32x4)0.f;
#pragma unroll
    for (int ks = 0; ks < 4; ++ks) {
      const int p0 = ks * 32 + g * 8;
      const int chunk = ks * 4 + g;
      bf16x8 th[2], tl[2];
#pragma unroll
      for (int t = 0; t < 2; ++t) {
        const int o_ = t * 16 + lr;
        const int idx = o_ * 128 + ((chunk ^ (o_ & 15)) << 3);
        th[t] = *(const bf16x8*)&sMtH[idx];
        tl[t] = *(const bf16x8*)&sMtL[idx];
      }
#pragma unroll
      for (int n = 0; n < 2; ++n) {
        const int cc = (wave * 2 + n) * 16 + lr;
        bf16x8 bh = *(const bf16x8*)(Bh + cc * NC + p0);
        bf16x8 bl = *(const bf16x8*)(Bl + cc * NC + p0);
#pragma unroll
        for (int t = 0; t < 2; ++t) {
          a3[t][n] = __builtin_amdgcn_mfma_f32_16x16x32_bf16(th[t], bh, a3[t][n], 0, 0, 0);
          a3[t][n] = __builtin_amdgcn_mfma_f32_16x16x32_bf16(th[t], bl, a3[t][n], 0, 0, 0);
          a3[t][n] = __builtin_amdgcn_mfma_f32_16x16x32_bf16(tl[t], bh, a3[t][n], 0, 0, 0);
        }
      }
    }
#pragma unroll
    for (int t = 0; t < 2; ++t)
#pragma unroll
      for (int n = 0; n < 2; ++n)
#pragma unroll
        for (int r = 0; r < 4; ++r) {
          const int o = so0 + t * 16 + g * 4 + r;
          const int cg = half * 128 + (wave * 2 + n) * 16 + lr;
          const size_t base = ((size_t)(b * 128 + o) * 8 + (cg >> 5)) * 64 + (cg & 31);
          float v = a3[t][n][r];
          __bf16 h = (__bf16)v;
          Aout[base] = h;
          Aout[base + 32] = (__bf16)(v - (float)h);
        }
  }
}

// ---------------- Pass 3: out[b] = [Af|Aa] @ [x;y] + c ----------------------
// grid (NL/128, NB), 512 thr = 8 waves (4 m-groups x 2 col-halves).
// Both S (rotation swizzle) and A (interleaved hi|lo, XOR swizzle) staged via
// gload_lds; counted-vmcnt double-buffer pipeline, zero VMEM in compute.
__global__ __launch_bounds__(512, 4) void k_pass3(
    const float* __restrict__ x, const float* __restrict__ y,
    const __bf16* __restrict__ A, const float* __restrict__ cvec,
    float* __restrict__ out)
{
  __shared__ float sS[2][32 * 128];     // 16KB each
  __shared__ __bf16 sA[2][128 * 64];    // 16KB each: row o x [hi 32 | lo 32]
  const int b = blockIdx.y;
  const int l0 = blockIdx.x * 128;
  const int tid = threadIdx.x;
  const int wave = tid >> 6, lane = tid & 63;
  const int lr = lane & 15, g = lane >> 4;
  const int mg = wave >> 1, ch = wave & 1;

  // S staging: slot=q*512+tid -> k=slot>>5, phys 16B chunk=slot&31,
  // logical chunk = (phys - 2*((k>>3)&3)) & 31   [rotation per g-group]
  int sk[2], sc[2];
#pragma unroll
  for (int q = 0; q < 2; ++q) {
    int slot = q * 512 + tid;
    int k = slot >> 5, pch = slot & 31;
    int gr = (k >> 3) & 3;
    sk[q] = k;
    sc[q] = ((pch - 2 * gr) & 31) * 4;
  }
  // A staging: slot=q*512+tid -> row=slot>>3, phys chunk=slot&7,
  // logical = phys ^ (row&7); elem offset = logical*8 (+32 handled by layout)
  int ar[2], ac[2];
#pragma unroll
  for (int q = 0; q < 2; ++q) {
    int slot = q * 512 + tid;
    int row = slot >> 3, pch = slot & 7;
    ar[q] = row;
    ac[q] = (pch ^ (row & 7)) * 8;
  }

  f32x4 acc[2][4];
#pragma unroll
  for (int t = 0; t < 2; ++t)
#pragma unroll
    for (int nt = 0; nt < 4; ++nt) acc[t][nt] = (f32x4)0.f;

  auto stage = [&](int buf, int s) {
    const float* S = (s < 4 ? x : y) + (size_t)b * NC * NL;
    const int chan0 = (s & 3) * 32;
#pragma unroll
    for (int q = 0; q < 2; ++q)
      gload_lds16(S + (size_t)(chan0 + sk[q]) * NL + l0 + sc[q],
                  &sS[buf][(q * 512 + tid) * 4]);
#pragma unroll
    for (int q = 0; q < 2; ++q)
      gload_lds16(A + ((size_t)(b * 128 + ar[q]) * 8 + s) * 64 + ac[q],
                  &sA[buf][(q * 512 + tid) * 8]);
  };

  stage(0, 0);
  stage(1, 1);

  for (int s = 0; s < 8; ++s) {
    const int cur = s & 1;
    if (s < 7) { asm volatile("s_waitcnt vmcnt(4)" ::: "memory"); }
    else       { asm volatile("s_waitcnt vmcnt(0)" ::: "memory"); }
    BAR();

    bf16x8 a_h[2], a_l[2];
#pragma unroll
    for (int t = 0; t < 2; ++t) {
      const int row = mg * 32 + t * 16 + lr;
      const __bf16* base = &sA[cur][row * 64];
      a_h[t] = *(const bf16x8*)(base + (g ^ (row & 7)) * 8);
      a_l[t] = *(const bf16x8*)(base + ((4 | g) ^ (row & 7)) * 8);
    }
    __builtin_amdgcn_s_setprio(1);
#pragma unroll
    for (int nt = 0; nt < 4; ++nt) {
      const int col = ch * 64 + nt * 16 + lr;
      const int base = ((((col >> 2) + 2 * g) & 31) << 2) + (col & 3);
      float e[8];
#pragma unroll
      for (int j = 0; j < 8; ++j) e[j] = sS[cur][(g * 8 + j) * 128 + base];
      bf16x8 bh, bl;
      split8(e, bh, bl);
#pragma unroll
      for (int t = 0; t < 2; ++t) {
        acc[t][nt] = __builtin_amdgcn_mfma_f32_16x16x32_bf16(a_h[t], bh, acc[t][nt], 0, 0, 0);
        acc[t][nt] = __builtin_amdgcn_mfma_f32_16x16x32_bf16(a_h[t], bl, acc[t][nt], 0, 0, 0);
        acc[t][nt] = __builtin_amdgcn_mfma_f32_16x16x32_bf16(a_l[t], bh, acc[t][nt], 0, 0, 0);
      }
    }
    __builtin_amdgcn_s_setprio(0);
    asm volatile("s_waitcnt lgkmcnt(0)" ::: "memory");
    BAR();
    if (s < 6) stage(cur, s + 2);
  }

  float* outb = out + (size_t)b * NC * NL;
#pragma unroll
  for (int t = 0; t < 2; ++t)
#pragma unroll
    for (int r = 0; r < 4; ++r) {
      const int row = mg * 32 + t * 16 + g * 4 + r;
      const float cv = cvec[b * NC + row];
#pragma unroll
      for (int nt = 0; nt < 4; ++nt)
        outb[(size_t)row * NL + l0 + ch * 64 + nt * 16 + lr] = acc[t][nt][r] + cv;
    }
}

extern "C" void kernel_launch(void* const* d_in, const int* in_sizes, int n_in,
                              void* d_out, int out_size, void* d_ws, size_t ws_size,
                              hipStream_t stream)
{
  const float* x = (const float*)d_in[0];
  const float* y = (const float*)d_in[1];
  const float* Wf = (const float*)d_in[2];
  const float* bfv = (const float*)d_in[3];
  const float* Wa = (const float*)d_in[4];
  const float* bav = (const float*)d_in[5];
  float* out = (float*)d_out;

  // ws: G | sx | sy | cvec | 8x weight-splits (bf16) | A (step-grouped hi|lo)
  float* G = (float*)d_ws;                       // NB*NC*NC
  float* sx = G + (size_t)NB * NC * NC;          // NB*NC
  float* sy = sx + NB * NC;                      // NB*NC
  float* cv = sy + NB * NC;                      // NB*NC
  __bf16* ws8 = (__bf16*)(cv + NB * NC);         // 8 * 16384 bf16
  __bf16* Aout = ws8 + 8 * 16384;                // NB*128*8*64 bf16 = 4MB

  k_prep<<<12, 256, 0, stream>>>(Wf, Wa, G, ws8);
  k_pass1<<<dim3(16, NB), 512, 0, stream>>>(x, y, G, sx, sy);
  k_p2<<<dim3(4, NB), 256, 0, stream>>>(G, ws8, Wf, Wa, bfv, bav, sx, sy, Aout, cv);
  k_pass3<<<dim3(NL / 128, NB), 512, 0, stream>>>(x, y, Aout, cv, out);
}

// Round 5
// 448.460 us; speedup vs baseline: 1.3846x; 1.0014x over previous
//
#include <hip/hip_runtime.h>
#include <math.h>

#define NB 32
#define NC 128
#define NL 8192
#define SPLITK 16
#define SQRT_L 90.50966799187809f

typedef float f32x4 __attribute__((ext_vector_type(4)));
typedef __bf16 bf16x8 __attribute__((ext_vector_type(8)));

#define BAR() __builtin_amdgcn_s_barrier()

__device__ inline void gload_lds16(const void* g, void* l) {
  __builtin_amdgcn_global_load_lds(
      (const __attribute__((address_space(1))) void*)g,
      (__attribute__((address_space(3))) void*)l, 16, 0, 0);
}

__device__ inline void split8(const float* e, bf16x8& hi, bf16x8& lo) {
#pragma unroll
  for (int j = 0; j < 8; ++j) {
    float f = e[j];
    __bf16 h = (__bf16)f;
    hi[j] = h;
    lo[j] = (__bf16)(f - (float)h);
  }
}

// ---------------- prep: split/transpose weights to bf16 hi/lo ----------------
// ws8 order: Wf_h, Wf_l, WfT_h, WfT_l, Wa_h, Wa_l, WaT_h, WaT_l (each 128x128)
__global__ __launch_bounds__(256, 2) void k_prep(
    const float* __restrict__ Wf, const float* __restrict__ Wa,
    __bf16* __restrict__ ws8)
{
  const int blk = blockIdx.x, t = threadIdx.x;
  const float* W = blk ? Wa : Wf;
  __bf16* Oh = ws8 + (blk ? 4 : 0) * 16384;
  __bf16* Ol = Oh + 16384;
  __bf16* Th = Ol + 16384;
  __bf16* Tl = Th + 16384;
  __shared__ float lds[NC * NC];
  for (int i = t; i < NC * NC; i += 256) {
    int r = i >> 7, c = i & 127;
    lds[r * 128 + (c ^ (r & 31))] = W[i];
  }
  __syncthreads();
  for (int i = t; i < NC * NC; i += 256) {
    int r = i >> 7, c = i & 127;
    float v = lds[r * 128 + (c ^ (r & 31))];
    __bf16 h = (__bf16)v;
    Oh[i] = h; Ol[i] = (__bf16)(v - (float)h);
    float vt = lds[c * 128 + (r ^ (c & 31))];  // W[c][r] -> T[r][c]
    __bf16 ht = (__bf16)vt;
    Th[i] = ht; Tl[i] = (__bf16)(vt - (float)ht);
  }
}

// ---------------- Pass 1: partial G = x[b][:,kchunk] @ y[b][:,kchunk]^T ------
// grid (SPLITK, NB), 512 thr = 8 waves; wave w owns rows [16w,16w+16).
// Counted-vmcnt double-buffer pipeline. NO atomics: plain stores of the
// 128x128 partial into P[kc][b] (P lives in d_out scratch), sx/sy partials
// into Psx/Psy; k_reduce sums them.
__global__ __launch_bounds__(512, 2) void k_pass1(
    const float* __restrict__ x, const float* __restrict__ y,
    float* __restrict__ P, float* __restrict__ Psx, float* __restrict__ Psy)
{
  __shared__ float ldsA[2][128 * 32];
  __shared__ float ldsB[2][128 * 32];
  const int b = blockIdx.y;
  const int kc = blockIdx.x;
  const int k0 = kc * (NL / SPLITK);
  const int tid = threadIdx.x;
  const int wave = tid >> 6, lane = tid & 63;
  const int lr = lane & 15, g = lane >> 4;
  const float* Xb = x + (size_t)b * NC * NL;
  const float* Yb = y + (size_t)b * NC * NL;

  // staging map: slot = q*512+tid -> row = slot>>3, phys chunk = slot&7,
  // logical chunk = phys ^ (row&7)  (16B chunks, 8 per 128B row)
  int srow[2], scol[2];
#pragma unroll
  for (int q = 0; q < 2; ++q) {
    int slot = q * 512 + tid;
    int row = slot >> 3, pch = slot & 7;
    srow[q] = row;
    scol[q] = (pch ^ (row & 7)) * 4;
  }

  f32x4 acc[8];
#pragma unroll
  for (int n = 0; n < 8; ++n) acc[n] = (f32x4)0.f;
  float rsx = 0.f;
  float rsy[8] = {0.f, 0.f, 0.f, 0.f, 0.f, 0.f, 0.f, 0.f};

  auto stage = [&](int buf, int s) {
    const int kk = k0 + s * 32;
#pragma unroll
    for (int q = 0; q < 2; ++q)
      gload_lds16(Xb + (size_t)srow[q] * NL + kk + scol[q], &ldsA[buf][(q * 512 + tid) * 4]);
#pragma unroll
    for (int q = 0; q < 2; ++q)
      gload_lds16(Yb + (size_t)srow[q] * NL + kk + scol[q], &ldsB[buf][(q * 512 + tid) * 4]);
  };

  stage(0, 0);
  stage(1, 1);

  for (int s = 0; s < 16; ++s) {
    const int cur = s & 1;
    if (s < 15) { asm volatile("s_waitcnt vmcnt(4)" ::: "memory"); }
    else        { asm volatile("s_waitcnt vmcnt(0)" ::: "memory"); }
    BAR();

    bf16x8 ah, al;
    {
      const int row = wave * 16 + lr;
      const float* base = &ldsA[cur][row * 32];
      f32x4 v0 = *(const f32x4*)(base + ((2 * g) ^ (row & 7)) * 4);
      f32x4 v1 = *(const f32x4*)(base + ((2 * g + 1) ^ (row & 7)) * 4);
      float e[8] = {v0[0], v0[1], v0[2], v0[3], v1[0], v1[1], v1[2], v1[3]};
#pragma unroll
      for (int j = 0; j < 8; ++j) rsx += e[j];
      split8(e, ah, al);
    }
    __builtin_amdgcn_s_setprio(1);
#pragma unroll
    for (int n = 0; n < 8; ++n) {
      const int row = n * 16 + lr;
      const float* base = &ldsB[cur][row * 32];
      f32x4 v0 = *(const f32x4*)(base + ((2 * g) ^ (row & 7)) * 4);
      f32x4 v1 = *(const f32x4*)(base + ((2 * g + 1) ^ (row & 7)) * 4);
      float e[8] = {v0[0], v0[1], v0[2], v0[3], v1[0], v1[1], v1[2], v1[3]};
      if (wave == 0) {
#pragma unroll
        for (int j = 0; j < 8; ++j) rsy[n] += e[j];
      }
      bf16x8 bh, bl;
      split8(e, bh, bl);
      acc[n] = __builtin_amdgcn_mfma_f32_16x16x32_bf16(ah, bh, acc[n], 0, 0, 0);
      acc[n] = __builtin_amdgcn_mfma_f32_16x16x32_bf16(ah, bl, acc[n], 0, 0, 0);
      acc[n] = __builtin_amdgcn_mfma_f32_16x16x32_bf16(al, bh, acc[n], 0, 0, 0);
    }
    __builtin_amdgcn_s_setprio(0);
    asm volatile("s_waitcnt lgkmcnt(0)" ::: "memory");
    BAR();
    if (s < 14) stage(cur, s + 2);
  }

  // plain stores of the partial tile (no atomics)
  float* Pb = P + ((size_t)kc * NB + b) * (NC * NC);
#pragma unroll
  for (int n = 0; n < 8; ++n)
#pragma unroll
    for (int r = 0; r < 4; ++r) {
      const int row = wave * 16 + g * 4 + r;
      const int col = n * 16 + lr;
      Pb[row * NC + col] = acc[n][r];
    }
  {
    float v = rsx;
    v += __shfl_xor(v, 16);
    v += __shfl_xor(v, 32);
    if (lane < 16) Psx[((size_t)kc * NB + b) * NC + wave * 16 + lr] = v;
  }
  if (wave == 0) {
#pragma unroll
    for (int n = 0; n < 8; ++n) {
      float v = rsy[n];
      v += __shfl_xor(v, 16);
      v += __shfl_xor(v, 32);
      if (lane < 16) Psy[((size_t)kc * NB + b) * NC + n * 16 + lr] = v;
    }
  }
}

// ---------------- reduce: G = sum_kc P[kc]; sx/sy likewise -------------------
// grid 514 x 256 thr. Blocks 0..511: G (1 f32x4/thread). 512: sx, 513: sy.
__global__ __launch_bounds__(256) void k_reduce(
    const float* __restrict__ P, const float* __restrict__ Psx,
    const float* __restrict__ Psy, float* __restrict__ G,
    float* __restrict__ sx, float* __restrict__ sy)
{
  const int blk = blockIdx.x, t = threadIdx.x;
  if (blk < 512) {
    const size_t i = (size_t)blk * 256 + t;  // f32x4 index within [b][.]
    const f32x4* P4 = (const f32x4*)P;
    f32x4 s = (f32x4)0.f;
#pragma unroll
    for (int kc = 0; kc < SPLITK; ++kc) s += P4[(size_t)kc * 131072 + i];
    ((f32x4*)G)[i] = s;
  } else {
    const f32x4* Pv = (const f32x4*)(blk == 512 ? Psx : Psy);
    f32x4* o = (f32x4*)(blk == 512 ? sx : sy);
    for (int j = t; j < 1024; j += 256) {
      f32x4 s = (f32x4)0.f;
#pragma unroll
      for (int kc = 0; kc < SPLITK; ++kc) s += Pv[kc * 1024 + j];
      o[j] = s;
    }
  }
}

// ---------------- Pass 2 (strip-parallel): grid (4, NB), 256 thr = 4 waves.
// Each block: full Mt = Wa*G^T (shared work, tiny), then its own 32-row strip:
// scores -> softmax -> attn -> Af|Aa into step-grouped A-layout.
// A layout: elem((b,o,c)) = ((b*128+o)*8 + (c>>5))*64 + (c&31) [+32 for lo]
__global__ __launch_bounds__(256, 2) void k_p2(
    const float* __restrict__ G, const __bf16* __restrict__ ws8,
    const float* __restrict__ Wf, const float* __restrict__ Wa,
    const float* __restrict__ bfv, const float* __restrict__ bav,
    const float* __restrict__ sx, const float* __restrict__ sy,
    __bf16* __restrict__ Aout, float* __restrict__ cvec)
{
  __shared__ __bf16 sMtH[NC * NC];   // 32KB; attn-hi reuses [0:4096]
  __shared__ __bf16 sMtL[NC * NC];   // 32KB; attn-lo reuses [0:4096]
  __shared__ float sSc[32 * 128];    // 16KB scores
  __shared__ float su[32];
  __shared__ float sv[128];

  const __bf16* Wf_h = ws8;
  const __bf16* Wf_l = ws8 + 16384;
  const __bf16* WfT_h = ws8 + 2 * 16384;
  const __bf16* WfT_l = ws8 + 3 * 16384;
  const __bf16* Wa_h = ws8 + 4 * 16384;
  const __bf16* Wa_l = ws8 + 5 * 16384;
  const __bf16* WaT_h = ws8 + 6 * 16384;
  const __bf16* WaT_l = ws8 + 7 * 16384;

  const int b = blockIdx.y;
  const int so0 = blockIdx.x * 32;
  const int tid = threadIdx.x;
  const int wave = tid >> 6, lane = tid & 63;
  const int lr = lane & 15, g = lane >> 4;

  // phase 0: su[o'] = Wf[so0+o'] . sx ; sv[p] = Wa[p] . sy
  if (tid < 32) {
    const f32x4* W4 = (const f32x4*)(Wf + (size_t)(so0 + tid) * NC);
    const f32x4* S4 = (const f32x4*)(sx + b * NC);
    float a = 0.f;
#pragma unroll
    for (int i = 0; i < 32; ++i) {
      f32x4 w = W4[i], s = S4[i];
      a += w[0] * s[0] + w[1] * s[1] + w[2] * s[2] + w[3] * s[3];
    }
    su[tid] = a;
  } else if (tid >= 128) {
    const int p = tid - 128;
    const f32x4* W4 = (const f32x4*)(Wa + (size_t)p * NC);
    const f32x4* S4 = (const f32x4*)(sy + b * NC);
    float a = 0.f;
#pragma unroll
    for (int i = 0; i < 32; ++i) {
      f32x4 w = W4[i], s = S4[i];
      a += w[0] * s[0] + w[1] * s[1] + w[2] * s[2] + w[3] * s[3];
    }
    sv[p] = a;
  }

  const float* Gb = G + (size_t)b * NC * NC;

  // GEMM1: Mt[p][f] = sum_a Wa[p][a]*G[f][a]; wave owns p-strip [32w,32w+32)
  {
    f32x4 a1[2][8];
#pragma unroll
    for (int t = 0; t < 2; ++t)
#pragma unroll
      for (int n = 0; n < 8; ++n) a1[t][n] = (f32x4)0.f;
#pragma unroll
    for (int ks = 0; ks < 4; ++ks) {
      const int a0 = ks * 32 + g * 8;
      bf16x8 wh[2], wl[2];
#pragma unroll
      for (int t = 0; t < 2; ++t) {
        const int p = wave * 32 + t * 16 + lr;
        wh[t] = *(const bf16x8*)(Wa_h + p * NC + a0);
        wl[t] = *(const bf16x8*)(Wa_l + p * NC + a0);
      }
#pragma unroll
      for (int n = 0; n < 8; ++n) {
        const int f = n * 16 + lr;
        f32x4 g0 = *(const f32x4*)(Gb + (size_t)f * NC + a0);
        f32x4 g1 = *(const f32x4*)(Gb + (size_t)f * NC + a0 + 4);
        float e[8] = {g0[0], g0[1], g0[2], g0[3], g1[0], g1[1], g1[2], g1[3]};
        bf16x8 gh, gl;
        split8(e, gh, gl);
#pragma unroll
        for (int t = 0; t < 2; ++t) {
          a1[t][n] = __builtin_amdgcn_mfma_f32_16x16x32_bf16(wh[t], gh, a1[t][n], 0, 0, 0);
          a1[t][n] = __builtin_amdgcn_mfma_f32_16x16x32_bf16(wh[t], gl, a1[t][n], 0, 0, 0);
          a1[t][n] = __builtin_amdgcn_mfma_f32_16x16x32_bf16(wl[t], gh, a1[t][n], 0, 0, 0);
        }
      }
    }
#pragma unroll
    for (int t = 0; t < 2; ++t)
#pragma unroll
      for (int n = 0; n < 8; ++n)
#pragma unroll
        for (int r = 0; r < 4; ++r) {
          const int p = wave * 32 + t * 16 + g * 4 + r;
          const int f = n * 16 + lr;
          const int idx = p * 128 + (((f >> 3) ^ (p & 7)) << 3) + (f & 7);
          float v = a1[t][n][r];
          __bf16 h = (__bf16)v;
          sMtH[idx] = h;
          sMtL[idx] = (__bf16)(v - (float)h);
        }
  }
  __syncthreads();

  // GEMM2: scores[o][p] = sum_f Wf[o][f]*Mt[p][f]; o in strip, wave owns 2 p-frags
  f32x4 s2[2][2];
#pragma unroll
  for (int t = 0; t < 2; ++t)
#pragma unroll
    for (int n = 0; n < 2; ++n) s2[t][n] = (f32x4)0.f;
#pragma unroll
  for (int ks = 0; ks < 4; ++ks) {
    const int f0 = ks * 32 + g * 8;
    const int chunk = ks * 4 + g;
    bf16x8 wh[2], wl[2];
#pragma unroll
    for (int t = 0; t < 2; ++t) {
      const int o = so0 + t * 16 + lr;
      wh[t] = *(const bf16x8*)(Wf_h + o * NC + f0);
      wl[t] = *(const bf16x8*)(Wf_l + o * NC + f0);
    }
#pragma unroll
    for (int n = 0; n < 2; ++n) {
      const int p = (wave * 2 + n) * 16 + lr;
      const int idx = p * 128 + ((chunk ^ (p & 7)) << 3);
      bf16x8 mh = *(const bf16x8*)&sMtH[idx];
      bf16x8 ml = *(const bf16x8*)&sMtL[idx];
#pragma unroll
      for (int t = 0; t < 2; ++t) {
        s2[t][n] = __builtin_amdgcn_mfma_f32_16x16x32_bf16(wh[t], mh, s2[t][n], 0, 0, 0);
        s2[t][n] = __builtin_amdgcn_mfma_f32_16x16x32_bf16(wh[t], ml, s2[t][n], 0, 0, 0);
        s2[t][n] = __builtin_amdgcn_mfma_f32_16x16x32_bf16(wl[t], mh, s2[t][n], 0, 0, 0);
      }
    }
  }
  __syncthreads();  // all waves done reading Mt (attn will overwrite region)

  // rank-1 terms, write scores f32 to sSc
#pragma unroll
  for (int n = 0; n < 2; ++n) {
    const int p = (wave * 2 + n) * 16 + lr;
    const float bap = bav[p];
    const float svp = sv[p] + 8192.0f * bap;
#pragma unroll
    for (int t = 0; t < 2; ++t)
#pragma unroll
      for (int r = 0; r < 4; ++r) {
        const int o_ = t * 16 + g * 4 + r;
        sSc[o_ * 128 + p] = s2[t][n][r] + su[o_] * bap + bfv[so0 + o_] * svp;
      }
  }
  __syncthreads();

  // softmax: row = tid>>3 (32 rows), j = tid&7 scans 16 cols; 8-lane reduce
  {
    const int row = tid >> 3, j = tid & 7;
    const float* sr = &sSc[row * 128 + j * 16];
    float m = -3.4e38f;
#pragma unroll
    for (int i = 0; i < 16; ++i) m = fmaxf(m, sr[i]);
    m = fmaxf(m, __shfl_xor(m, 1));
    m = fmaxf(m, __shfl_xor(m, 2));
    m = fmaxf(m, __shfl_xor(m, 4));
    float e[16], sum = 0.f;
#pragma unroll
    for (int i = 0; i < 16; ++i) { e[i] = __expf(sr[i] - m); sum += e[i]; }
    sum += __shfl_xor(sum, 1);
    sum += __shfl_xor(sum, 2);
    sum += __shfl_xor(sum, 4);
    const float inv = 1.f / (sum * SQRT_L);
    float c = 0.f;
    bf16x8 hv[2], lv[2];
#pragma unroll
    for (int i = 0; i < 16; ++i) {
      const int p = j * 16 + i;
      float a = e[i] * inv;
      c += a * (bfv[p] + bav[p]);
      __bf16 h = (__bf16)a;
      hv[i >> 3][i & 7] = h;
      lv[i >> 3][i & 7] = (__bf16)(a - (float)h);
    }
    // attn LDS (reuse sMt[0:4096]): row stride 128 elems, 16-chunk XOR swizzle
#pragma unroll
    for (int q = 0; q < 2; ++q) {
      const int chunk = (j * 2 + q) ^ (row & 15);
      *(bf16x8*)&sMtH[row * 128 + chunk * 8] = hv[q];
      *(bf16x8*)&sMtL[row * 128 + chunk * 8] = lv[q];
    }
    c += __shfl_xor(c, 1);
    c += __shfl_xor(c, 2);
    c += __shfl_xor(c, 4);
    if (j == 0) cvec[b * NC + so0 + row] = c;
  }
  __syncthreads();

  // GEMM3: Af = attn*WfT (cols 0..127), Aa = attn*WaT (cols 128..255)
#pragma unroll
  for (int half = 0; half < 2; ++half) {
    const __bf16* Bh = half ? WaT_h : WfT_h;
    const __bf16* Bl = half ? WaT_l : WfT_l;
    f32x4 a3[2][2];
#pragma unroll
    for (int t = 0; t < 2; ++t)
#pragma unroll
      for (int n = 0; n < 2; ++n) a3[t][n] = (f32x4)0.f;
#pragma unroll
    for (int ks = 0; ks < 4; ++ks) {
      const int p0 = ks * 32 + g * 8;
      const int chunk = ks * 4 + g;
      bf16x8 th[2], tl[2];
#pragma unroll
      for (int t = 0; t < 2; ++t) {
        const int o_ = t * 16 + lr;
        const int idx = o_ * 128 + ((chunk ^ (o_ & 15)) << 3);
        th[t] = *(const bf16x8*)&sMtH[idx];
        tl[t] = *(const bf16x8*)&sMtL[idx];
      }
#pragma unroll
      for (int n = 0; n < 2; ++n) {
        const int cc = (wave * 2 + n) * 16 + lr;
        bf16x8 bh = *(const bf16x8*)(Bh + cc * NC + p0);
        bf16x8 bl = *(const bf16x8*)(Bl + cc * NC + p0);
#pragma unroll
        for (int t = 0; t < 2; ++t) {
          a3[t][n] = __builtin_amdgcn_mfma_f32_16x16x32_bf16(th[t], bh, a3[t][n], 0, 0, 0);
          a3[t][n] = __builtin_amdgcn_mfma_f32_16x16x32_bf16(th[t], bl, a3[t][n], 0, 0, 0);
          a3[t][n] = __builtin_amdgcn_mfma_f32_16x16x32_bf16(tl[t], bh, a3[t][n], 0, 0, 0);
        }
      }
    }
#pragma unroll
    for (int t = 0; t < 2; ++t)
#pragma unroll
      for (int n = 0; n < 2; ++n)
#pragma unroll
        for (int r = 0; r < 4; ++r) {
          const int o = so0 + t * 16 + g * 4 + r;
          const int cg = half * 128 + (wave * 2 + n) * 16 + lr;
          const size_t base = ((size_t)(b * 128 + o) * 8 + (cg >> 5)) * 64 + (cg & 31);
          float v = a3[t][n][r];
          __bf16 h = (__bf16)v;
          Aout[base] = h;
          Aout[base + 32] = (__bf16)(v - (float)h);
        }
  }
}

// ---------------- Pass 3: out[b] = [Af|Aa] @ [x;y] + c ----------------------
// grid (NL/128, NB), 512 thr = 8 waves (4 m-groups x 2 col-halves).
// Both S (rotation swizzle) and A (interleaved hi|lo, XOR swizzle) staged via
// gload_lds; counted-vmcnt double-buffer pipeline, zero VMEM in compute.
__global__ __launch_bounds__(512, 4) void k_pass3(
    const float* __restrict__ x, const float* __restrict__ y,
    const __bf16* __restrict__ A, const float* __restrict__ cvec,
    float* __restrict__ out)
{
  __shared__ float sS[2][32 * 128];     // 16KB each
  __shared__ __bf16 sA[2][128 * 64];    // 16KB each: row o x [hi 32 | lo 32]
  const int b = blockIdx.y;
  const int l0 = blockIdx.x * 128;
  const int tid = threadIdx.x;
  const int wave = tid >> 6, lane = tid & 63;
  const int lr = lane & 15, g = lane >> 4;
  const int mg = wave >> 1, ch = wave & 1;

  // S staging: slot=q*512+tid -> k=slot>>5, phys 16B chunk=slot&31,
  // logical chunk = (phys - 2*((k>>3)&3)) & 31   [rotation per g-group]
  int sk[2], sc[2];
#pragma unroll
  for (int q = 0; q < 2; ++q) {
    int slot = q * 512 + tid;
    int k = slot >> 5, pch = slot & 31;
    int gr = (k >> 3) & 3;
    sk[q] = k;
    sc[q] = ((pch - 2 * gr) & 31) * 4;
  }
  // A staging: slot=q*512+tid -> row=slot>>3, phys chunk=slot&7,
  // logical = phys ^ (row&7); elem offset = logical*8 (+32 handled by layout)
  int ar[2], ac[2];
#pragma unroll
  for (int q = 0; q < 2; ++q) {
    int slot = q * 512 + tid;
    int row = slot >> 3, pch = slot & 7;
    ar[q] = row;
    ac[q] = (pch ^ (row & 7)) * 8;
  }

  f32x4 acc[2][4];
#pragma unroll
  for (int t = 0; t < 2; ++t)
#pragma unroll
    for (int nt = 0; nt < 4; ++nt) acc[t][nt] = (f32x4)0.f;

  auto stage = [&](int buf, int s) {
    const float* S = (s < 4 ? x : y) + (size_t)b * NC * NL;
    const int chan0 = (s & 3) * 32;
#pragma unroll
    for (int q = 0; q < 2; ++q)
      gload_lds16(S + (size_t)(chan0 + sk[q]) * NL + l0 + sc[q],
                  &sS[buf][(q * 512 + tid) * 4]);
#pragma unroll
    for (int q = 0; q < 2; ++q)
      gload_lds16(A + ((size_t)(b * 128 + ar[q]) * 8 + s) * 64 + ac[q],
                  &sA[buf][(q * 512 + tid) * 8]);
  };

  stage(0, 0);
  stage(1, 1);

  for (int s = 0; s < 8; ++s) {
    const int cur = s & 1;
    if (s < 7) { asm volatile("s_waitcnt vmcnt(4)" ::: "memory"); }
    else       { asm volatile("s_waitcnt vmcnt(0)" ::: "memory"); }
    BAR();

    bf16x8 a_h[2], a_l[2];
#pragma unroll
    for (int t = 0; t < 2; ++t) {
      const int row = mg * 32 + t * 16 + lr;
      const __bf16* base = &sA[cur][row * 64];
      a_h[t] = *(const bf16x8*)(base + (g ^ (row & 7)) * 8);
      a_l[t] = *(const bf16x8*)(base + ((4 | g) ^ (row & 7)) * 8);
    }
    __builtin_amdgcn_s_setprio(1);
#pragma unroll
    for (int nt = 0; nt < 4; ++nt) {
      const int col = ch * 64 + nt * 16 + lr;
      const int base = ((((col >> 2) + 2 * g) & 31) << 2) + (col & 3);
      float e[8];
#pragma unroll
      for (int j = 0; j < 8; ++j) e[j] = sS[cur][(g * 8 + j) * 128 + base];
      bf16x8 bh, bl;
      split8(e, bh, bl);
#pragma unroll
      for (int t = 0; t < 2; ++t) {
        acc[t][nt] = __builtin_amdgcn_mfma_f32_16x16x32_bf16(a_h[t], bh, acc[t][nt], 0, 0, 0);
        acc[t][nt] = __builtin_amdgcn_mfma_f32_16x16x32_bf16(a_h[t], bl, acc[t][nt], 0, 0, 0);
        acc[t][nt] = __builtin_amdgcn_mfma_f32_16x16x32_bf16(a_l[t], bh, acc[t][nt], 0, 0, 0);
      }
    }
    __builtin_amdgcn_s_setprio(0);
    asm volatile("s_waitcnt lgkmcnt(0)" ::: "memory");
    BAR();
    if (s < 6) stage(cur, s + 2);
  }

  float* outb = out + (size_t)b * NC * NL;
#pragma unroll
  for (int t = 0; t < 2; ++t)
#pragma unroll
    for (int r = 0; r < 4; ++r) {
      const int row = mg * 32 + t * 16 + g * 4 + r;
      const float cv = cvec[b * NC + row];
#pragma unroll
      for (int nt = 0; nt < 4; ++nt)
        outb[(size_t)row * NL + l0 + ch * 64 + nt * 16 + lr] = acc[t][nt][r] + cv;
    }
}

extern "C" void kernel_launch(void* const* d_in, const int* in_sizes, int n_in,
                              void* d_out, int out_size, void* d_ws, size_t ws_size,
                              hipStream_t stream)
{
  const float* x = (const float*)d_in[0];
  const float* y = (const float*)d_in[1];
  const float* Wf = (const float*)d_in[2];
  const float* bfv = (const float*)d_in[3];
  const float* Wa = (const float*)d_in[4];
  const float* bav = (const float*)d_in[5];
  float* out = (float*)d_out;

  // ws: G | sx | sy | cvec | Psx | Psy | 8x weight-splits (bf16) | A
  float* G = (float*)d_ws;                       // NB*NC*NC
  float* sx = G + (size_t)NB * NC * NC;          // NB*NC
  float* sy = sx + NB * NC;                      // NB*NC
  float* cv = sy + NB * NC;                      // NB*NC
  float* Psx = cv + NB * NC;                     // SPLITK*NB*NC
  float* Psy = Psx + SPLITK * NB * NC;           // SPLITK*NB*NC
  __bf16* ws8 = (__bf16*)(Psy + SPLITK * NB * NC); // 8 * 16384 bf16
  __bf16* Aout = ws8 + 8 * 16384;                // NB*128*8*64 bf16 = 4MB

  // G-partials live in d_out scratch (33.5MB << 134MB); pass3 overwrites later.
  float* P = out;                                // SPLITK*NB*NC*NC

  k_prep<<<2, 256, 0, stream>>>(Wf, Wa, ws8);
  k_pass1<<<dim3(SPLITK, NB), 512, 0, stream>>>(x, y, P, Psx, Psy);
  k_reduce<<<514, 256, 0, stream>>>(P, Psx, Psy, G, sx, sy);
  k_p2<<<dim3(4, NB), 256, 0, stream>>>(G, ws8, Wf, Wa, bfv, bav, sx, sy, Aout, cv);
  k_pass3<<<dim3(NL / 128, NB), 512, 0, stream>>>(x, y, Aout, cv, out);
}